// Round 6
// baseline (164.673 us; speedup 1.0000x reference)
//
#include <hip/hip_runtime.h>

// z(8,128,64,64) f32, codes(16,256,8) f32
// out: soft(8,64,64,128) | hard(8,64,64,128) | idx(8,64,64,16) as f32
#define NPOS 32768
#define CCH  128
#define LL   16
#define KK   256
#define CD   8

typedef float f32x2 __attribute__((ext_vector_type(2)));

#if __has_builtin(__builtin_amdgcn_exp2f)
#define EXP2F(x) __builtin_amdgcn_exp2f(x)
#else
#define EXP2F(x) __builtin_exp2f(x)
#endif

#define LOG2E 1.4426950408889634f   // scale h,c: exp2(-sqrt(d2')) == exp(-dist)  (R4-proven)
#define LN2   0.6931471805599453f   // un-scale acc (codes carry LOG2E)

// block: 256 threads = 2 latents x 128 positions, P=1.
// grid: 256 pos-chunks x 8 l-chunks = 2048 blocks = 8 blocks/CU -> 8 waves/SIMD.
// Codes come through the scalar path (s_load, wave-uniform) -> no LDS, SGPR operands.
__global__ __launch_bounds__(256, 8) void soft_hard_enc(
    const float* __restrict__ z, const float* __restrict__ codes,
    float* __restrict__ out)
{
    const int tid = (int)threadIdx.x;
    const int bid = (int)blockIdx.x;
    const int posBase = (bid >> 3) * 128;
    const int lBase   = (bid & 7) * 2;

    const int l  = __builtin_amdgcn_readfirstlane(tid >> 7);  // wave-uniform latent
    const int p  = tid & 127;
    const int l4 = lBase + l;
    const int pos = posBase + p;
    const int b   = pos >> 12;
    const int wh  = pos & 4095;

    // hv: 8 channels, scaled, packed channel-major (natural pairs, no duplication)
    const float* zp = z + (((size_t)(b * CCH + l4 * CD)) << 12) + wh;
    f32x2 hs[4];
#pragma unroll
    for (int cc = 0; cc < 4; ++cc) {
        hs[cc][0] = LOG2E * zp[((size_t)(2 * cc))     << 12];
        hs[cc][1] = LOG2E * zp[((size_t)(2 * cc + 1)) << 12];
    }

    // wave-uniform codebook slice -> scalar loads (s_load_dwordx16 per pair)
    const float* __restrict__ cp = codes + (size_t)l4 * KK * CD;

    f32x2 acc[4];
#pragma unroll
    for (int cc = 0; cc < 4; ++cc) acc[cc] = (f32x2){0.f, 0.f};
    float ssum = 0.0f;
    float bd   = 3.4e38f;
    int   bk   = 0;

#pragma unroll 2
    for (int j = 0; j < KK / 2; ++j) {
        const float* ck2 = cp + j * 16;       // 2 codes = 64 B, uniform
#pragma unroll
        for (int t = 0; t < 2; ++t) {
            const float* ck = ck2 + t * CD;
            // cs pairs are consecutive dwords -> consecutive SGPRs (VOP3P sgpr-pair src)
            f32x2 d2p = (f32x2){0.f, 0.f};
            f32x2 cs0 = (f32x2){LOG2E * ck[0], LOG2E * ck[1]};
            f32x2 cs1 = (f32x2){LOG2E * ck[2], LOG2E * ck[3]};
            f32x2 cs2 = (f32x2){LOG2E * ck[4], LOG2E * ck[5]};
            f32x2 cs3 = (f32x2){LOG2E * ck[6], LOG2E * ck[7]};
            f32x2 df0 = hs[0] - cs0;
            f32x2 df1 = hs[1] - cs1;
            f32x2 df2 = hs[2] - cs2;
            f32x2 df3 = hs[3] - cs3;
            d2p = __builtin_elementwise_fma(df0, df0, d2p);
            d2p = __builtin_elementwise_fma(df1, df1, d2p);
            d2p = __builtin_elementwise_fma(df2, df2, d2p);
            d2p = __builtin_elementwise_fma(df3, df3, d2p);
            float d2 = d2p[0] + d2p[1];

            float s = __builtin_amdgcn_sqrtf(d2);   // direct form: argmin-exact (R0/R1/R4)
            float e = EXP2F(-s);
            ssum += e;

            f32x2 ep = (f32x2){e, e};               // op_sel broadcast
            acc[0] = __builtin_elementwise_fma(ep, cs0, acc[0]);
            acc[1] = __builtin_elementwise_fma(ep, cs1, acc[1]);
            acc[2] = __builtin_elementwise_fma(ep, cs2, acc[2]);
            acc[3] = __builtin_elementwise_fma(ep, cs3, acc[3]);

            const int k = 2 * j + t;                // uniform (SGPR cndmask source)
            if (d2 < bd) { bd = d2; bk = k; }       // strict < = np.argmin first occurrence
        }
    }

    const float sc = LN2 / ssum;                    // un-scale + softmax normalize
    float a[CD];
#pragma unroll
    for (int cc = 0; cc < 4; ++cc) {
        a[2 * cc]     = acc[cc][0] * sc;
        a[2 * cc + 1] = acc[cc][1] * sc;
    }

    const size_t obase = (size_t)pos * CCH + (size_t)(l4 * CD);
    *(float4*)&out[obase]     = (float4){a[0], a[1], a[2], a[3]};
    *(float4*)&out[obase + 4] = (float4){a[4], a[5], a[6], a[7]};

    // hard: per-lane gather from L2-hot codes
    const float* hp = codes + ((size_t)(l4 * KK + bk)) * CD;
    float4 h0 = *(const float4*)(hp);
    float4 h1 = *(const float4*)(hp + 4);
    float* outh = out + (size_t)NPOS * CCH;
    *(float4*)&outh[obase]     = h0;
    *(float4*)&outh[obase + 4] = h1;

    float* outi = out + (size_t)2 * NPOS * CCH;
    outi[(size_t)pos * LL + l4] = (float)bk;
}

extern "C" void kernel_launch(void* const* d_in, const int* in_sizes, int n_in,
                              void* d_out, int out_size, void* d_ws, size_t ws_size,
                              hipStream_t stream) {
    const float* z     = (const float*)d_in[0];
    const float* codes = (const float*)d_in[1];
    float* out = (float*)d_out;
    soft_hard_enc<<<dim3(2048), dim3(256), 0, stream>>>(z, codes, out);
}

// Round 7
// 154.424 us; speedup vs baseline: 1.0664x; 1.0664x over previous
//
#include <hip/hip_runtime.h>

// z(8,128,64,64) f32, codes(16,256,8) f32
// out: soft(8,64,64,128) | hard(8,64,64,128) | idx(8,64,64,16) as f32
#define NPOS 32768
#define CCH  128
#define LL   16
#define KK   256
#define CD   8

typedef float f32x2 __attribute__((ext_vector_type(2)));

#if __has_builtin(__builtin_amdgcn_exp2f)
#define EXP2F(x) __builtin_amdgcn_exp2f(x)
#else
#define EXP2F(x) __builtin_exp2f(x)
#endif

// exp(-dist) = exp2(-sqrt(d2 * LOG2E^2)); single v_mul per code, no operand scaling
#define LOG2E_SQ 2.0813689810056077f

// block: 256 threads = 2 latents x 128 positions, P=1.
// grid: 256 pos-chunks x 8 l-chunks = 2048 blocks = 8 blocks/CU -> 8 waves/SIMD,
// exactly one full residency of the machine (32 waves/CU).
// Codes stream through the scalar path (wave-uniform s_load_dwordx16) -> no LDS,
// VOP3P consumes code pairs directly from consecutive SGPRs.
__global__ __launch_bounds__(256, 8) void soft_hard_enc(
    const float* __restrict__ z, const float* __restrict__ codes,
    float* __restrict__ out)
{
    const int tid = (int)threadIdx.x;
    const int bid = (int)blockIdx.x;
    const int posBase = (bid >> 3) * 128;
    const int lBase   = (bid & 7) * 2;

    const int l  = __builtin_amdgcn_readfirstlane(tid >> 7);  // wave-uniform latent
    const int p  = tid & 127;
    const int l4 = lBase + l;
    const int pos = posBase + p;
    const int b   = pos >> 12;
    const int wh  = pos & 4095;

    // hv: 8 channels RAW (no scaling), packed channel-major; lane-coalesced loads
    const float* zp = z + (((size_t)(b * CCH + l4 * CD)) << 12) + wh;
    f32x2 hs[4];
#pragma unroll
    for (int cc = 0; cc < 4; ++cc) {
        hs[cc][0] = zp[((size_t)(2 * cc))     << 12];
        hs[cc][1] = zp[((size_t)(2 * cc + 1)) << 12];
    }

    // wave-uniform codebook slice -> scalar loads
    const float* __restrict__ cp = codes + (size_t)l4 * KK * CD;

    f32x2 acc[4];
#pragma unroll
    for (int cc = 0; cc < 4; ++cc) acc[cc] = (f32x2){0.f, 0.f};
    float ssum = 0.0f;
    float bd   = 3.4e38f;
    int   bk   = 0;

#pragma unroll 2
    for (int j = 0; j < KK / 2; ++j) {     // 2 codes per j (one s_load_dwordx16)
        const float* ck2 = cp + j * 16;
#pragma unroll
        for (int t = 0; t < 2; ++t) {
            const float* ck = ck2 + t * CD;
            // raw code channel-pairs: consecutive dwords -> consecutive SGPRs
            f32x2 cs0 = (f32x2){ck[0], ck[1]};
            f32x2 cs1 = (f32x2){ck[2], ck[3]};
            f32x2 cs2 = (f32x2){ck[4], ck[5]};
            f32x2 cs3 = (f32x2){ck[6], ck[7]};

            // direct squared distance on RAW values: err ~ eps*d2 (idx exact R0/R1)
            f32x2 d2p = (f32x2){0.f, 0.f};
            f32x2 df0 = hs[0] - cs0;
            f32x2 df1 = hs[1] - cs1;
            f32x2 df2 = hs[2] - cs2;
            f32x2 df3 = hs[3] - cs3;
            d2p = __builtin_elementwise_fma(df0, df0, d2p);
            d2p = __builtin_elementwise_fma(df1, df1, d2p);
            d2p = __builtin_elementwise_fma(df2, df2, d2p);
            d2p = __builtin_elementwise_fma(df3, df3, d2p);
            float d2 = d2p[0] + d2p[1];

            // temperature folded post-hoc: one v_mul instead of scaling operands
            float s = __builtin_amdgcn_sqrtf(d2 * LOG2E_SQ);
            float e = EXP2F(-s);
            ssum += e;

            f32x2 ep = (f32x2){e, e};             // op_sel broadcast
            acc[0] = __builtin_elementwise_fma(ep, cs0, acc[0]);
            acc[1] = __builtin_elementwise_fma(ep, cs1, acc[1]);
            acc[2] = __builtin_elementwise_fma(ep, cs2, acc[2]);
            acc[3] = __builtin_elementwise_fma(ep, cs3, acc[3]);

            // argmin on RAW d2; strict < = np.argmin first occurrence
            const int k = 2 * j + t;              // uniform cndmask source
            if (d2 < bd) { bd = d2; bk = k; }
        }
    }

    const float sc = 1.0f / ssum;                 // raw codes -> plain normalize
    float a[CD];
#pragma unroll
    for (int cc = 0; cc < 4; ++cc) {
        a[2 * cc]     = acc[cc][0] * sc;
        a[2 * cc + 1] = acc[cc][1] * sc;
    }

    const size_t obase = (size_t)pos * CCH + (size_t)(l4 * CD);
    *(float4*)&out[obase]     = (float4){a[0], a[1], a[2], a[3]};
    *(float4*)&out[obase + 4] = (float4){a[4], a[5], a[6], a[7]};

    // hard: per-lane gather from L2-hot codes
    const float* hp = codes + ((size_t)(l4 * KK + bk)) * CD;
    float4 h0 = *(const float4*)(hp);
    float4 h1 = *(const float4*)(hp + 4);
    float* outh = out + (size_t)NPOS * CCH;
    *(float4*)&outh[obase]     = h0;
    *(float4*)&outh[obase + 4] = h1;

    float* outi = out + (size_t)2 * NPOS * CCH;
    outi[(size_t)pos * LL + l4] = (float)bk;
}

extern "C" void kernel_launch(void* const* d_in, const int* in_sizes, int n_in,
                              void* d_out, int out_size, void* d_ws, size_t ws_size,
                              hipStream_t stream) {
    const float* z     = (const float*)d_in[0];
    const float* codes = (const float*)d_in[1];
    float* out = (float*)d_out;
    soft_hard_enc<<<dim3(2048), dim3(256), 0, stream>>>(z, codes, out);
}